// Round 5
// baseline (832.800 us; speedup 1.0000x reference)
//
#include <hip/hip_runtime.h>

#define NN 50000
#define NE 600000

typedef __attribute__((ext_vector_type(8))) short short8;
typedef __attribute__((ext_vector_type(4))) float f32x4;

#define SWZ(row) ((((row) & 7) << 4) ^ (((row) & 8) << 2))

__device__ __forceinline__ float silu_f(float x) { return x / (1.0f + __expf(-x)); }

__device__ __forceinline__ unsigned short f2bf(float f) {
    unsigned u = __builtin_bit_cast(unsigned, f);
    unsigned r = u + 0x7FFFu + ((u >> 16) & 1u);   // RNE
    return (unsigned short)(r >> 16);
}

// LDS-only barrier (no vmcnt drain).
__device__ __forceinline__ void lds_barrier() {
    asm volatile("s_waitcnt lgkmcnt(0)" ::: "memory");
    __builtin_amdgcn_s_barrier();
    asm volatile("" ::: "memory");
}

// ---------------------------------------------------------------------------
// K0: h (fp32) -> h_bf16
// ---------------------------------------------------------------------------
__global__ __launch_bounds__(512) void k_prep(const float* __restrict__ h,
                                              unsigned short* __restrict__ hb)
{
    const int nchunks = NN * 128 / 8;   // 800000
    for (int i = blockIdx.x * blockDim.x + threadIdx.x; i < nchunks;
         i += gridDim.x * blockDim.x) {
        const float4* p = (const float4*)(h + (size_t)i * 8);
        float4 x = p[0], y = p[1];
        short8 v;
        v[0] = f2bf(x.x); v[1] = f2bf(x.y); v[2] = f2bf(x.z); v[3] = f2bf(x.w);
        v[4] = f2bf(y.x); v[5] = f2bf(y.y); v[6] = f2bf(y.z); v[7] = f2bf(y.w);
        *(short8*)(hb + (size_t)i * 8) = v;
    }
}

// ---------------------------------------------------------------------------
// CSR build: deg count -> 1-block scan -> scatter
// ---------------------------------------------------------------------------
__global__ __launch_bounds__(256) void k_deg(const int* __restrict__ ei,
                                             int* __restrict__ deg)
{
    for (int e = blockIdx.x * 256 + threadIdx.x; e < NE; e += gridDim.x * 256)
        atomicAdd(&deg[ei[e]], 1);
}

__global__ __launch_bounds__(1024) void k_scan(const int* __restrict__ deg,
                                               int* __restrict__ rowptr,
                                               int* __restrict__ cursor)
{
    __shared__ int sb[1024];
    const int t = threadIdx.x;
    const int CH = 49;                  // 1024*49 = 50176 >= NN
    const int base = t * CH;
    int s = 0;
    for (int j = 0; j < CH; ++j) {
        int idx = base + j;
        if (idx < NN) s += deg[idx];
    }
    sb[t] = s;
    __syncthreads();
    for (int off = 1; off < 1024; off <<= 1) {
        int v = (t >= off) ? sb[t - off] : 0;
        __syncthreads();
        sb[t] += v;
        __syncthreads();
    }
    int run = sb[t] - s;                // exclusive prefix of this thread's chunk
    for (int j = 0; j < CH; ++j) {
        int idx = base + j;
        if (idx < NN) {
            rowptr[idx] = run;
            cursor[idx] = run;
            run += deg[idx];
        }
    }
    if (t == 1023) rowptr[NN] = sb[1023];
}

__global__ __launch_bounds__(256) void k_scatter(const int* __restrict__ ei,
                                                 int* __restrict__ cursor,
                                                 int* __restrict__ elist)
{
    for (int e = blockIdx.x * 256 + threadIdx.x; e < NE; e += gridDim.x * 256) {
        int pos = atomicAdd(&cursor[ei[e]], 1);
        elist[pos] = e;
    }
}

// ---------------------------------------------------------------------------
// K1: fused edge pipeline — NO heavy atomics. Writes ef (fp32, LLC-cacheable)
// and per-edge trans = coord_diff * wq (12B). 8 waves, weights in registers.
// ---------------------------------------------------------------------------
__global__ __launch_bounds__(512, 4) void k_edge(
    const unsigned short* __restrict__ hb, const float* __restrict__ coord,
    const int* __restrict__ ei,
    const float* __restrict__ w_e1, const float* __restrict__ b_e1,
    const float* __restrict__ w_e2, const float* __restrict__ b_e2,
    const float* __restrict__ w_c1, const float* __restrict__ b_c1,
    const float* __restrict__ w_c2,
    float* __restrict__ ef, float* __restrict__ trans)
{
    __shared__ unsigned short A1s[64 * 256];    // 32768 B  (h-pair; later EF bf16)
    __shared__ unsigned short A2s[64 * 128];    // 16384 B  (t1 bf16)
    __shared__ float rad[64];
    __shared__ float dxyz[64][3];
    __shared__ float wqp[8][64];

    const int tid  = threadIdx.x;
    const int wv   = tid >> 6, lane = tid & 63;
    const int l4   = lane >> 4, li = lane & 15;
    const int n    = wv * 16 + li;              // this wave's output column

    // ---- weight B-fragments -> registers ----
    short8 bw1[8], bw2[4], bwc[4];
    #pragma unroll
    for (int ks = 0; ks < 8; ++ks) {
        short8 t;
        #pragma unroll
        for (int j = 0; j < 8; ++j) t[j] = f2bf(w_e1[(ks * 32 + l4 * 8 + j) * 128 + n]);
        bw1[ks] = t;
    }
    #pragma unroll
    for (int ks = 0; ks < 4; ++ks) {
        short8 t, u;
        #pragma unroll
        for (int j = 0; j < 8; ++j) {
            t[j] = f2bf(w_e2[(ks * 32 + l4 * 8 + j) * 128 + n]);
            u[j] = f2bf(w_c1[(ks * 32 + l4 * 8 + j) * 128 + n]);
        }
        bw2[ks] = t; bwc[ks] = u;
    }
    const float wradv = w_e1[256 * 128 + n];
    const float b1v = b_e1[n], b2v = b_e2[n], bc1v = b_c1[n], wc2v = w_c2[n];

    const f32x4 z4 = {0.f, 0.f, 0.f, 0.f};

    for (int t = blockIdx.x; t < NE / 64; t += gridDim.x) {
        const int ebase = t * 64;
        // ---- stage radial + coord-diff ----
        if (tid < 64) {
            int e = ebase + tid;
            int r = ei[e], c = ei[NE + e];
            float dx = coord[r * 3 + 0] - coord[c * 3 + 0];
            float dy = coord[r * 3 + 1] - coord[c * 3 + 1];
            float dz = coord[r * 3 + 2] - coord[c * 3 + 2];
            dxyz[tid][0] = dx; dxyz[tid][1] = dy; dxyz[tid][2] = dz;
            rad[tid] = dx * dx + dy * dy + dz * dz;
        }
        // ---- stage A1: 64 edges x 32 chunks (16B) ----
        {
            int le = tid >> 3;
            int e = ebase + le;
            int r = ei[e], c = ei[NE + e];
            const unsigned short* hr = hb + (size_t)r * 128;
            const unsigned short* hc = hb + (size_t)c * 128;
            #pragma unroll
            for (int i = 0; i < 4; ++i) {
                int chunk = i * 8 + (tid & 7);
                short8 v = (chunk < 16) ? *(const short8*)(hr + chunk * 8)
                                        : *(const short8*)(hc + (chunk - 16) * 8);
                int off = le * 512 + ((chunk * 16) ^ SWZ(le));
                *(short8*)((char*)A1s + off) = v;
            }
        }
        lds_barrier();   // B1: A1s/rad ready

        // ---- GEMM1: [64 x 256] @ [256 x 16] ----
        f32x4 acc[4];
        acc[0] = z4; acc[1] = z4; acc[2] = z4; acc[3] = z4;
        for (int ks = 0; ks < 8; ++ks) {
            const int kb = ks * 64 + l4 * 16;
            #pragma unroll
            for (int mf = 0; mf < 4; ++mf) {
                int row = mf * 16 + li;
                short8 a = *(const short8*)((const char*)A1s + row * 512 + (kb ^ SWZ(row)));
                acc[mf] = __builtin_amdgcn_mfma_f32_16x16x32_bf16(a, bw1[ks], acc[mf], 0, 0, 0);
            }
        }
        // epilogue1: + radial rank-1 + bias, silu -> A2s (t1, bf16 swizzled)
        #pragma unroll
        for (int mf = 0; mf < 4; ++mf)
            #pragma unroll
            for (int r = 0; r < 4; ++r) {
                int row = mf * 16 + l4 * 4 + r;
                float v = silu_f(acc[mf][r] + rad[row] * wradv + b1v);
                int off = row * 256 + ((n * 2) ^ SWZ(row));
                *(unsigned short*)((char*)A2s + off) = f2bf(v);
            }
        lds_barrier();   // B2: A2s ready; A1s reads done

        // ---- GEMM2: [64 x 128] @ [128 x 16] ----
        acc[0] = z4; acc[1] = z4; acc[2] = z4; acc[3] = z4;
        for (int ks = 0; ks < 4; ++ks) {
            const int kb = ks * 64 + l4 * 16;
            #pragma unroll
            for (int mf = 0; mf < 4; ++mf) {
                int row = mf * 16 + li;
                short8 a = *(const short8*)((const char*)A2s + row * 256 + (kb ^ SWZ(row)));
                acc[mf] = __builtin_amdgcn_mfma_f32_16x16x32_bf16(a, bw2[ks], acc[mf], 0, 0, 0);
            }
        }
        // epilogue2: EF bf16 -> A1s, ef fp32 -> global (plain store; LLC keeps it
        // for k_agg's gather). No atomics.
        #pragma unroll
        for (int mf = 0; mf < 4; ++mf)
            #pragma unroll
            for (int r = 0; r < 4; ++r) {
                int row = mf * 16 + l4 * 4 + r;
                int e = ebase + row;
                float v = silu_f(acc[mf][r] + b2v);
                int off = row * 256 + ((n * 2) ^ SWZ(row));
                *(unsigned short*)((char*)A1s + off) = f2bf(v);
                ef[(size_t)e * 128 + n] = v;
            }
        lds_barrier();   // B3: EF(A1s) ready; A2s reads done

        // ---- GEMM-c1: [64 x 128] @ [128 x 16] ----
        acc[0] = z4; acc[1] = z4; acc[2] = z4; acc[3] = z4;
        for (int ks = 0; ks < 4; ++ks) {
            const int kb = ks * 64 + l4 * 16;
            #pragma unroll
            for (int mf = 0; mf < 4; ++mf) {
                int row = mf * 16 + li;
                short8 a = *(const short8*)((const char*)A1s + row * 256 + (kb ^ SWZ(row)));
                acc[mf] = __builtin_amdgcn_mfma_f32_16x16x32_bf16(a, bwc[ks], acc[mf], 0, 0, 0);
            }
        }
        // wq partials: silu(c1)*w_c2, reduce over 16 lanes
        #pragma unroll
        for (int mf = 0; mf < 4; ++mf)
            #pragma unroll
            for (int r = 0; r < 4; ++r) {
                float p = silu_f(acc[mf][r] + bc1v) * wc2v;
                p += __shfl_xor(p, 1); p += __shfl_xor(p, 2);
                p += __shfl_xor(p, 4); p += __shfl_xor(p, 8);
                if (li == 0) wqp[wv][mf * 16 + l4 * 4 + r] = p;
            }
        lds_barrier();   // B4: wqp ready; A1s reads done

        if (tid < 64) {
            float wq = 0.f;
            #pragma unroll
            for (int w = 0; w < 8; ++w) wq += wqp[w][tid];
            int e = ebase + tid;
            trans[(size_t)e * 3 + 0] = dxyz[tid][0] * wq;
            trans[(size_t)e * 3 + 1] = dxyz[tid][1] * wq;
            trans[(size_t)e * 3 + 2] = dxyz[tid][2] * wq;
        }
        // no B5 needed (see dependency audit in round 4)
    }
}

// ---------------------------------------------------------------------------
// K-agg: atomic-free segment sums via CSR gather. One wave per node:
//   agg[n]       = sum_{e in row(n)} ef[e]          (fp32, exact)
//   coord_new[n] = coord[n] + sum trans[e] / max(deg,1)
// ---------------------------------------------------------------------------
__global__ __launch_bounds__(512) void k_agg(
    const float* __restrict__ ef, const float* __restrict__ trans,
    const int* __restrict__ rowptr, const int* __restrict__ elist,
    const float* __restrict__ coord,
    float* __restrict__ agg, float* __restrict__ coord_new)
{
    const int wv = threadIdx.x >> 6, lane = threadIdx.x & 63;
    const int nw = gridDim.x * 8;
    for (int node = blockIdx.x * 8 + wv; node < NN; node += nw) {
        const int s = rowptr[node], e2 = rowptr[node + 1];
        float a0 = 0.f, a1 = 0.f;
        for (int i = s; i < e2; ++i) {
            int e = elist[i];
            a0 += ef[(size_t)e * 128 + lane];
            a1 += ef[(size_t)e * 128 + 64 + lane];
        }
        agg[(size_t)node * 128 + lane]      = a0;
        agg[(size_t)node * 128 + 64 + lane] = a1;
        if (lane < 3) {
            float ts = 0.f;
            for (int i = s; i < e2; ++i) ts += trans[(size_t)elist[i] * 3 + lane];
            coord_new[node * 3 + lane] =
                coord[node * 3 + lane] + ts / fmaxf((float)(e2 - s), 1.f);
        }
    }
}

// ---------------------------------------------------------------------------
// K2: fused node MLP (h_new only; coord handled in k_agg).
// ---------------------------------------------------------------------------
__global__ __launch_bounds__(512, 4) void k_node(
    const unsigned short* __restrict__ hb, const float* __restrict__ h,
    const float* __restrict__ agg,
    const float* __restrict__ w_n1, const float* __restrict__ b_n1,
    const float* __restrict__ w_n2, const float* __restrict__ b_n2,
    float* __restrict__ h_new)
{
    __shared__ unsigned short As[64 * 256];     // 32768 B
    __shared__ unsigned short Us[64 * 128];     // 16384 B

    const int tid  = threadIdx.x;
    const int wv   = tid >> 6, lane = tid & 63;
    const int l4   = lane >> 4, li = lane & 15;
    const int n    = wv * 16 + li;

    short8 bw1[8], bw2[4];
    #pragma unroll
    for (int ks = 0; ks < 8; ++ks) {
        short8 t;
        #pragma unroll
        for (int j = 0; j < 8; ++j) t[j] = f2bf(w_n1[(ks * 32 + l4 * 8 + j) * 128 + n]);
        bw1[ks] = t;
    }
    #pragma unroll
    for (int ks = 0; ks < 4; ++ks) {
        short8 t;
        #pragma unroll
        for (int j = 0; j < 8; ++j) t[j] = f2bf(w_n2[(ks * 32 + l4 * 8 + j) * 128 + n]);
        bw2[ks] = t;
    }
    const float b1v = b_n1[n], b2v = b_n2[n];

    const f32x4 z4 = {0.f, 0.f, 0.f, 0.f};
    const int ntiles = (NN + 63) / 64;          // 782

    for (int t = blockIdx.x; t < ntiles; t += gridDim.x) {
        const int nbase = t * 64;
        {
            int ln = tid >> 3;
            int node = nbase + ln;
            #pragma unroll
            for (int i = 0; i < 4; ++i) {
                int chunk = i * 8 + (tid & 7);
                short8 v;
                if (node < NN) {
                    if (chunk < 16) {
                        v = *(const short8*)(hb + (size_t)node * 128 + chunk * 8);
                    } else {
                        const float4* p = (const float4*)(agg + (size_t)node * 128 + (chunk - 16) * 8);
                        float4 x = p[0], y = p[1];
                        v[0] = f2bf(x.x); v[1] = f2bf(x.y); v[2] = f2bf(x.z); v[3] = f2bf(x.w);
                        v[4] = f2bf(y.x); v[5] = f2bf(y.y); v[6] = f2bf(y.z); v[7] = f2bf(y.w);
                    }
                } else v = (short8)0;
                int off = ln * 512 + ((chunk * 16) ^ SWZ(ln));
                *(short8*)((char*)As + off) = v;
            }
        }
        lds_barrier();   // B1

        // GEMM1: K=256
        f32x4 acc[4];
        acc[0] = z4; acc[1] = z4; acc[2] = z4; acc[3] = z4;
        for (int ks = 0; ks < 8; ++ks) {
            const int kb = ks * 64 + l4 * 16;
            #pragma unroll
            for (int mf = 0; mf < 4; ++mf) {
                int row = mf * 16 + li;
                short8 a = *(const short8*)((const char*)As + row * 512 + (kb ^ SWZ(row)));
                acc[mf] = __builtin_amdgcn_mfma_f32_16x16x32_bf16(a, bw1[ks], acc[mf], 0, 0, 0);
            }
        }
        #pragma unroll
        for (int mf = 0; mf < 4; ++mf)
            #pragma unroll
            for (int r = 0; r < 4; ++r) {
                int row = mf * 16 + l4 * 4 + r;
                float v = silu_f(acc[mf][r] + b1v);
                int off = row * 256 + ((n * 2) ^ SWZ(row));
                *(unsigned short*)((char*)Us + off) = f2bf(v);
            }
        lds_barrier();   // B2: Us ready; As reads done

        // GEMM2: K=128
        acc[0] = z4; acc[1] = z4; acc[2] = z4; acc[3] = z4;
        for (int ks = 0; ks < 4; ++ks) {
            const int kb = ks * 64 + l4 * 16;
            #pragma unroll
            for (int mf = 0; mf < 4; ++mf) {
                int row = mf * 16 + li;
                short8 a = *(const short8*)((const char*)Us + row * 256 + (kb ^ SWZ(row)));
                acc[mf] = __builtin_amdgcn_mfma_f32_16x16x32_bf16(a, bw2[ks], acc[mf], 0, 0, 0);
            }
        }
        #pragma unroll
        for (int mf = 0; mf < 4; ++mf)
            #pragma unroll
            for (int r = 0; r < 4; ++r) {
                int row = mf * 16 + l4 * 4 + r;
                int node = nbase + row;
                if (node < NN) {
                    float v = acc[mf][r] + b2v + h[(size_t)node * 128 + n];
                    __builtin_nontemporal_store(v, &h_new[(size_t)node * 128 + n]);
                }
            }
        // no trailing barrier needed
    }
}

extern "C" void kernel_launch(void* const* d_in, const int* in_sizes, int n_in,
                              void* d_out, int out_size, void* d_ws, size_t ws_size,
                              hipStream_t stream)
{
    const float* h     = (const float*)d_in[0];
    const float* coord = (const float*)d_in[1];
    const int*   ei    = (const int*)d_in[2];
    const float* w_e1  = (const float*)d_in[3];
    const float* b_e1  = (const float*)d_in[4];
    const float* w_e2  = (const float*)d_in[5];
    const float* b_e2  = (const float*)d_in[6];
    const float* w_n1  = (const float*)d_in[7];
    const float* b_n1  = (const float*)d_in[8];
    const float* w_n2  = (const float*)d_in[9];
    const float* b_n2  = (const float*)d_in[10];
    const float* w_c1  = (const float*)d_in[11];
    const float* b_c1  = (const float*)d_in[12];
    const float* w_c2  = (const float*)d_in[13];

    float* h_new     = (float*)d_out;
    float* coord_new = h_new + (size_t)NN * 128;
    float* ef        = coord_new + (size_t)NN * 3;

    // ws layout (~48.8 MB; round-1 proved >= 52 MB available)
    float*          agg    = (float*)d_ws;                          // [NN*128] f32
    unsigned short* hb     = (unsigned short*)(agg + (size_t)NN * 128); // [NN*128] bf16
    float*          trans  = (float*)(hb + (size_t)NN * 128);       // [NE*3] f32
    int*            deg    = (int*)(trans + (size_t)NE * 3);        // [NN]
    int*            rowptr = deg + NN;                              // [NN+1]
    int*            cursor = rowptr + NN + 1;                       // [NN]
    int*            elist  = cursor + NN;                           // [NE]

    hipMemsetAsync(deg, 0, NN * sizeof(int), stream);

    k_prep   <<<1024, 512, 0, stream>>>(h, hb);
    k_deg    <<<1024, 256, 0, stream>>>(ei, deg);
    k_scan   <<<1,   1024, 0, stream>>>(deg, rowptr, cursor);
    k_scatter<<<1024, 256, 0, stream>>>(ei, cursor, elist);
    k_edge   <<<512,  512, 0, stream>>>(hb, coord, ei, w_e1, b_e1, w_e2, b_e2,
                                        w_c1, b_c1, w_c2, ef, trans);
    k_agg    <<<2048, 512, 0, stream>>>(ef, trans, rowptr, elist, coord,
                                        agg, coord_new);
    k_node   <<<512,  512, 0, stream>>>(hb, h, agg, w_n1, b_n1, w_n2, b_n2, h_new);
}

// Round 6
// 719.385 us; speedup vs baseline: 1.1577x; 1.1577x over previous
//
#include <hip/hip_runtime.h>

#define NN 50000
#define NE 600000

typedef __attribute__((ext_vector_type(8))) short short8;
typedef __attribute__((ext_vector_type(4))) float f32x4;

#define SWZ(row) ((((row) & 7) << 4) ^ (((row) & 8) << 2))

__device__ __forceinline__ float silu_f(float x) { return x / (1.0f + __expf(-x)); }

__device__ __forceinline__ unsigned short f2bf(float f) {
    unsigned u = __builtin_bit_cast(unsigned, f);
    unsigned r = u + 0x7FFFu + ((u >> 16) & 1u);   // RNE
    return (unsigned short)(r >> 16);
}
__device__ __forceinline__ float bf2f(unsigned short s) {
    unsigned u = ((unsigned)s) << 16;
    return __builtin_bit_cast(float, u);
}

// LDS-only barrier (no vmcnt drain) — atomics/stores stay in flight.
__device__ __forceinline__ void lds_barrier() {
    asm volatile("s_waitcnt lgkmcnt(0)" ::: "memory");
    __builtin_amdgcn_s_barrier();
    asm volatile("" ::: "memory");
}

// ---------------------------------------------------------------------------
// K0: h (fp32) -> h_bf16
// ---------------------------------------------------------------------------
__global__ __launch_bounds__(512) void k_prep(const float* __restrict__ h,
                                              unsigned short* __restrict__ hb)
{
    const int nchunks = NN * 128 / 8;   // 800000
    for (int i = blockIdx.x * blockDim.x + threadIdx.x; i < nchunks;
         i += gridDim.x * blockDim.x) {
        const float4* p = (const float4*)(h + (size_t)i * 8);
        float4 x = p[0], y = p[1];
        short8 v;
        v[0] = f2bf(x.x); v[1] = f2bf(x.y); v[2] = f2bf(x.z); v[3] = f2bf(x.w);
        v[4] = f2bf(y.x); v[5] = f2bf(y.y); v[6] = f2bf(y.z); v[7] = f2bf(y.w);
        *(short8*)(hb + (size_t)i * 8) = v;
    }
}

// ---------------------------------------------------------------------------
// CSR build: deg count -> 1-block scan -> scatter
// ---------------------------------------------------------------------------
__global__ __launch_bounds__(256) void k_deg(const int* __restrict__ ei,
                                             int* __restrict__ deg)
{
    for (int e = blockIdx.x * 256 + threadIdx.x; e < NE; e += gridDim.x * 256)
        atomicAdd(&deg[ei[e]], 1);
}

__global__ __launch_bounds__(1024) void k_scan(const int* __restrict__ deg,
                                               int* __restrict__ rowptr,
                                               int* __restrict__ cursor)
{
    __shared__ int sb[1024];
    const int t = threadIdx.x;
    const int CH = 49;                  // 1024*49 = 50176 >= NN
    const int base = t * CH;
    int s = 0;
    for (int j = 0; j < CH; ++j) {
        int idx = base + j;
        if (idx < NN) s += deg[idx];
    }
    sb[t] = s;
    __syncthreads();
    for (int off = 1; off < 1024; off <<= 1) {
        int v = (t >= off) ? sb[t - off] : 0;
        __syncthreads();
        sb[t] += v;
        __syncthreads();
    }
    int run = sb[t] - s;
    for (int j = 0; j < CH; ++j) {
        int idx = base + j;
        if (idx < NN) {
            rowptr[idx] = run;
            cursor[idx] = run;
            run += deg[idx];
        }
    }
    if (t == 1023) rowptr[NN] = sb[1023];
}

__global__ __launch_bounds__(256) void k_scatter(const int* __restrict__ ei,
                                                 int* __restrict__ cursor,
                                                 int* __restrict__ elist)
{
    for (int e = blockIdx.x * 256 + threadIdx.x; e < NE; e += gridDim.x * 256) {
        int pos = atomicAdd(&cursor[ei[e]], 1);
        elist[pos] = e;
    }
}

// ---------------------------------------------------------------------------
// K1: fused edge pipeline, CSR-ordered tiles (rows sorted within tile).
// Per tile: stage -> GEMM1 -> GEMM2 (ef nt-store, EF bf16 in LDS) ->
// GEMM-c1 + per-segment agg reduction (one atomic per distinct row) ->
// wq reduce -> per-segment tsum atomics. 4 lgkm barriers.
// ---------------------------------------------------------------------------
__global__ __launch_bounds__(512, 4) void k_edge(
    const unsigned short* __restrict__ hb, const float* __restrict__ coord,
    const int* __restrict__ ei, const int* __restrict__ elist,
    const float* __restrict__ w_e1, const float* __restrict__ b_e1,
    const float* __restrict__ w_e2, const float* __restrict__ b_e2,
    const float* __restrict__ w_c1, const float* __restrict__ b_c1,
    const float* __restrict__ w_c2,
    float* __restrict__ ef, float* __restrict__ agg,
    float* __restrict__ tsum)
{
    __shared__ unsigned short A1s[64 * 256];    // 32 KB (h-pair; later EF bf16)
    __shared__ unsigned short A2s[64 * 128];    // 16 KB (t1 bf16)
    __shared__ float rad[64];
    __shared__ float dxyz[64][3];
    __shared__ int   es_s[64];                  // original edge ids
    __shared__ int   seg_start[65];             // segment table (rows sorted)
    __shared__ int   seg_row[64];
    __shared__ int   nseg_s;
    __shared__ float wqp[8][64];
    __shared__ float wqs[64];

    const int tid  = threadIdx.x;
    const int wv   = tid >> 6, lane = tid & 63;
    const int l4   = lane >> 4, li = lane & 15;
    const int n    = wv * 16 + li;              // this wave's output column

    // ---- weight B-fragments -> registers ----
    short8 bw1[8], bw2[4], bwc[4];
    #pragma unroll
    for (int ks = 0; ks < 8; ++ks) {
        short8 t;
        #pragma unroll
        for (int j = 0; j < 8; ++j) t[j] = f2bf(w_e1[(ks * 32 + l4 * 8 + j) * 128 + n]);
        bw1[ks] = t;
    }
    #pragma unroll
    for (int ks = 0; ks < 4; ++ks) {
        short8 t, u;
        #pragma unroll
        for (int j = 0; j < 8; ++j) {
            t[j] = f2bf(w_e2[(ks * 32 + l4 * 8 + j) * 128 + n]);
            u[j] = f2bf(w_c1[(ks * 32 + l4 * 8 + j) * 128 + n]);
        }
        bw2[ks] = t; bwc[ks] = u;
    }
    const float wradv = w_e1[256 * 128 + n];
    const float b1v = b_e1[n], b2v = b_e2[n], bc1v = b_c1[n], wc2v = w_c2[n];

    const f32x4 z4 = {0.f, 0.f, 0.f, 0.f};

    for (int t = blockIdx.x; t < NE / 64; t += gridDim.x) {
        const int ebase = t * 64;
        // ---- wave 0: indices, radial, coord-diff, segment table ----
        if (tid < 64) {
            int e = elist[ebase + tid];
            int r = ei[e], c = ei[NE + e];
            es_s[tid] = e;
            float dx = coord[r * 3 + 0] - coord[c * 3 + 0];
            float dy = coord[r * 3 + 1] - coord[c * 3 + 1];
            float dz = coord[r * 3 + 2] - coord[c * 3 + 2];
            dxyz[tid][0] = dx; dxyz[tid][1] = dy; dxyz[tid][2] = dz;
            rad[tid] = dx * dx + dy * dy + dz * dz;
            // segment table via ballot-compaction (rows sorted in tile)
            int prev = __shfl_up(r, 1);
            bool flag = (lane == 0) || (r != prev);
            unsigned long long mask = __ballot(flag);
            if (flag) {
                int pos = __popcll(mask & ((1ull << lane) - 1ull));
                seg_start[pos] = lane;
                seg_row[pos]   = r;
            }
            if (lane == 0) {
                int ns = __popcll(mask);
                nseg_s = ns;
                seg_start[ns] = 64;
            }
        }
        // ---- stage A1: 64 edges x 32 chunks (16B) ----
        {
            int le = tid >> 3;
            int e = elist[ebase + le];
            int r = ei[e], c = ei[NE + e];
            const unsigned short* hr = hb + (size_t)r * 128;
            const unsigned short* hc = hb + (size_t)c * 128;
            #pragma unroll
            for (int i = 0; i < 4; ++i) {
                int chunk = i * 8 + (tid & 7);
                short8 v = (chunk < 16) ? *(const short8*)(hr + chunk * 8)
                                        : *(const short8*)(hc + (chunk - 16) * 8);
                int off = le * 512 + ((chunk * 16) ^ SWZ(le));
                *(short8*)((char*)A1s + off) = v;
            }
        }
        lds_barrier();   // B1: A1s/rad/seg/es ready

        // ---- GEMM1: [64 x 256] @ [256 x 16] ----
        f32x4 acc[4];
        acc[0] = z4; acc[1] = z4; acc[2] = z4; acc[3] = z4;
        for (int ks = 0; ks < 8; ++ks) {
            const int kb = ks * 64 + l4 * 16;
            #pragma unroll
            for (int mf = 0; mf < 4; ++mf) {
                int row = mf * 16 + li;
                short8 a = *(const short8*)((const char*)A1s + row * 512 + (kb ^ SWZ(row)));
                acc[mf] = __builtin_amdgcn_mfma_f32_16x16x32_bf16(a, bw1[ks], acc[mf], 0, 0, 0);
            }
        }
        #pragma unroll
        for (int mf = 0; mf < 4; ++mf)
            #pragma unroll
            for (int r = 0; r < 4; ++r) {
                int row = mf * 16 + l4 * 4 + r;
                float v = silu_f(acc[mf][r] + rad[row] * wradv + b1v);
                int off = row * 256 + ((n * 2) ^ SWZ(row));
                *(unsigned short*)((char*)A2s + off) = f2bf(v);
            }
        lds_barrier();   // B2: A2s ready; A1s reads done

        // ---- GEMM2: [64 x 128] @ [128 x 16] ----
        acc[0] = z4; acc[1] = z4; acc[2] = z4; acc[3] = z4;
        for (int ks = 0; ks < 4; ++ks) {
            const int kb = ks * 64 + l4 * 16;
            #pragma unroll
            for (int mf = 0; mf < 4; ++mf) {
                int row = mf * 16 + li;
                short8 a = *(const short8*)((const char*)A2s + row * 256 + (kb ^ SWZ(row)));
                acc[mf] = __builtin_amdgcn_mfma_f32_16x16x32_bf16(a, bw2[ks], acc[mf], 0, 0, 0);
            }
        }
        // epilogue2: EF bf16 -> A1s, ef fp32 nt-store (scattered by elist; each
        // 16-lane group writes a full contiguous 64B sector -> no alloc fetch)
        #pragma unroll
        for (int mf = 0; mf < 4; ++mf)
            #pragma unroll
            for (int r = 0; r < 4; ++r) {
                int row = mf * 16 + l4 * 4 + r;
                float v = silu_f(acc[mf][r] + b2v);
                int off = row * 256 + ((n * 2) ^ SWZ(row));
                *(unsigned short*)((char*)A1s + off) = f2bf(v);
                int e = es_s[row];
                __builtin_nontemporal_store(v, &ef[(size_t)e * 128 + n]);
            }
        lds_barrier();   // B3: EF(A1s) ready; A2s reads done

        // ---- GEMM-c1: [64 x 128] @ [128 x 16] ----
        acc[0] = z4; acc[1] = z4; acc[2] = z4; acc[3] = z4;
        for (int ks = 0; ks < 4; ++ks) {
            const int kb = ks * 64 + l4 * 16;
            #pragma unroll
            for (int mf = 0; mf < 4; ++mf) {
                int row = mf * 16 + li;
                short8 a = *(const short8*)((const char*)A1s + row * 256 + (kb ^ SWZ(row)));
                acc[mf] = __builtin_amdgcn_mfma_f32_16x16x32_bf16(a, bwc[ks], acc[mf], 0, 0, 0);
            }
        }
        // ---- per-segment agg reduction from EF (A1s bf16) ----
        // one atomic per (distinct row x col): ~7x128 per tile vs 64x128.
        {
            const int col = tid & 127;
            const int ns  = nseg_s;
            for (int s = tid >> 7; s < ns; s += 4) {
                int i0 = seg_start[s], i1 = seg_start[s + 1];
                float sum = 0.f;
                for (int i = i0; i < i1; ++i) {
                    unsigned short raw = *(const unsigned short*)
                        ((const char*)A1s + i * 256 + ((col * 2) ^ SWZ(i)));
                    sum += bf2f(raw);
                }
                atomicAdd(&agg[(size_t)seg_row[s] * 128 + col], sum);
            }
        }
        // wq partials: silu(c1)*w_c2, reduce over 16 lanes
        #pragma unroll
        for (int mf = 0; mf < 4; ++mf)
            #pragma unroll
            for (int r = 0; r < 4; ++r) {
                float p = silu_f(acc[mf][r] + bc1v) * wc2v;
                p += __shfl_xor(p, 1); p += __shfl_xor(p, 2);
                p += __shfl_xor(p, 4); p += __shfl_xor(p, 8);
                if (li == 0) wqp[wv][mf * 16 + l4 * 4 + r] = p;
            }
        lds_barrier();   // B4: wqp ready; A1s reads (GEMM-c1 + agg-red) done

        // ---- wave 0: wq finalize + per-segment tsum atomics ----
        // Reads only wave0-written LDS (wqp finalized at B4; dxyz/seg/wqs are
        // wave0-local) -> no trailing barrier needed before next staging.
        if (tid < 64) {
            float wq = 0.f;
            #pragma unroll
            for (int w = 0; w < 8; ++w) wq += wqp[w][tid];
            wqs[tid] = wq;
            int ns = nseg_s;
            for (int s = lane; s < ns; s += 64) {
                int i0 = seg_start[s], i1 = seg_start[s + 1];
                float tx = 0.f, ty = 0.f, tz = 0.f;
                for (int i = i0; i < i1; ++i) {
                    float w = wqs[i];
                    tx += dxyz[i][0] * w;
                    ty += dxyz[i][1] * w;
                    tz += dxyz[i][2] * w;
                }
                int rr = seg_row[s];
                atomicAdd(&tsum[rr * 3 + 0], tx);
                atomicAdd(&tsum[rr * 3 + 1], ty);
                atomicAdd(&tsum[rr * 3 + 2], tz);
            }
        }
    }
}

// ---------------------------------------------------------------------------
// K2: fused node MLP + coord_new (deg from rowptr). 2 lgkm barriers per tile.
// ---------------------------------------------------------------------------
__global__ __launch_bounds__(512, 4) void k_node(
    const unsigned short* __restrict__ hb, const float* __restrict__ h,
    const float* __restrict__ agg,
    const float* __restrict__ w_n1, const float* __restrict__ b_n1,
    const float* __restrict__ w_n2, const float* __restrict__ b_n2,
    const float* __restrict__ coord, const float* __restrict__ tsum,
    const int* __restrict__ rowptr,
    float* __restrict__ h_new, float* __restrict__ coord_new)
{
    __shared__ unsigned short As[64 * 256];     // 32 KB
    __shared__ unsigned short Us[64 * 128];     // 16 KB

    const int tid  = threadIdx.x;
    const int wv   = tid >> 6, lane = tid & 63;
    const int l4   = lane >> 4, li = lane & 15;
    const int n    = wv * 16 + li;

    short8 bw1[8], bw2[4];
    #pragma unroll
    for (int ks = 0; ks < 8; ++ks) {
        short8 t;
        #pragma unroll
        for (int j = 0; j < 8; ++j) t[j] = f2bf(w_n1[(ks * 32 + l4 * 8 + j) * 128 + n]);
        bw1[ks] = t;
    }
    #pragma unroll
    for (int ks = 0; ks < 4; ++ks) {
        short8 t;
        #pragma unroll
        for (int j = 0; j < 8; ++j) t[j] = f2bf(w_n2[(ks * 32 + l4 * 8 + j) * 128 + n]);
        bw2[ks] = t;
    }
    const float b1v = b_n1[n], b2v = b_n2[n];

    const f32x4 z4 = {0.f, 0.f, 0.f, 0.f};
    const int ntiles = (NN + 63) / 64;          // 782

    for (int t = blockIdx.x; t < ntiles; t += gridDim.x) {
        const int nbase = t * 64;
        {
            int ln = tid >> 3;
            int node = nbase + ln;
            #pragma unroll
            for (int i = 0; i < 4; ++i) {
                int chunk = i * 8 + (tid & 7);
                short8 v;
                if (node < NN) {
                    if (chunk < 16) {
                        v = *(const short8*)(hb + (size_t)node * 128 + chunk * 8);
                    } else {
                        const float4* p = (const float4*)(agg + (size_t)node * 128 + (chunk - 16) * 8);
                        float4 x = p[0], y = p[1];
                        v[0] = f2bf(x.x); v[1] = f2bf(x.y); v[2] = f2bf(x.z); v[3] = f2bf(x.w);
                        v[4] = f2bf(y.x); v[5] = f2bf(y.y); v[6] = f2bf(y.z); v[7] = f2bf(y.w);
                    }
                } else v = (short8)0;
                int off = ln * 512 + ((chunk * 16) ^ SWZ(ln));
                *(short8*)((char*)As + off) = v;
            }
        }
        lds_barrier();   // B1

        // GEMM1: K=256
        f32x4 acc[4];
        acc[0] = z4; acc[1] = z4; acc[2] = z4; acc[3] = z4;
        for (int ks = 0; ks < 8; ++ks) {
            const int kb = ks * 64 + l4 * 16;
            #pragma unroll
            for (int mf = 0; mf < 4; ++mf) {
                int row = mf * 16 + li;
                short8 a = *(const short8*)((const char*)As + row * 512 + (kb ^ SWZ(row)));
                acc[mf] = __builtin_amdgcn_mfma_f32_16x16x32_bf16(a, bw1[ks], acc[mf], 0, 0, 0);
            }
        }
        #pragma unroll
        for (int mf = 0; mf < 4; ++mf)
            #pragma unroll
            for (int r = 0; r < 4; ++r) {
                int row = mf * 16 + l4 * 4 + r;
                float v = silu_f(acc[mf][r] + b1v);
                int off = row * 256 + ((n * 2) ^ SWZ(row));
                *(unsigned short*)((char*)Us + off) = f2bf(v);
            }
        lds_barrier();   // B2: Us ready; As reads done

        // GEMM2: K=128
        acc[0] = z4; acc[1] = z4; acc[2] = z4; acc[3] = z4;
        for (int ks = 0; ks < 4; ++ks) {
            const int kb = ks * 64 + l4 * 16;
            #pragma unroll
            for (int mf = 0; mf < 4; ++mf) {
                int row = mf * 16 + li;
                short8 a = *(const short8*)((const char*)Us + row * 256 + (kb ^ SWZ(row)));
                acc[mf] = __builtin_amdgcn_mfma_f32_16x16x32_bf16(a, bw2[ks], acc[mf], 0, 0, 0);
            }
        }
        #pragma unroll
        for (int mf = 0; mf < 4; ++mf)
            #pragma unroll
            for (int r = 0; r < 4; ++r) {
                int row = mf * 16 + l4 * 4 + r;
                int node = nbase + row;
                if (node < NN) {
                    float v = acc[mf][r] + b2v + h[(size_t)node * 128 + n];
                    __builtin_nontemporal_store(v, &h_new[(size_t)node * 128 + n]);
                }
            }
        if (tid < 64) {
            int node = nbase + tid;
            if (node < NN) {
                int deg = rowptr[node + 1] - rowptr[node];
                float m = fmaxf((float)deg, 1.0f);
                coord_new[node * 3 + 0] = coord[node * 3 + 0] + tsum[node * 3 + 0] / m;
                coord_new[node * 3 + 1] = coord[node * 3 + 1] + tsum[node * 3 + 1] / m;
                coord_new[node * 3 + 2] = coord[node * 3 + 2] + tsum[node * 3 + 2] / m;
            }
        }
        // no trailing barrier: next staging writes As (not read by GEMM2);
        // Us(t+1) writes happen after B1(t+1).
    }
}

extern "C" void kernel_launch(void* const* d_in, const int* in_sizes, int n_in,
                              void* d_out, int out_size, void* d_ws, size_t ws_size,
                              hipStream_t stream)
{
    const float* h     = (const float*)d_in[0];
    const float* coord = (const float*)d_in[1];
    const int*   ei    = (const int*)d_in[2];
    const float* w_e1  = (const float*)d_in[3];
    const float* b_e1  = (const float*)d_in[4];
    const float* w_e2  = (const float*)d_in[5];
    const float* b_e2  = (const float*)d_in[6];
    const float* w_n1  = (const float*)d_in[7];
    const float* b_n1  = (const float*)d_in[8];
    const float* w_n2  = (const float*)d_in[9];
    const float* b_n2  = (const float*)d_in[10];
    const float* w_c1  = (const float*)d_in[11];
    const float* b_c1  = (const float*)d_in[12];
    const float* w_c2  = (const float*)d_in[13];

    float* h_new     = (float*)d_out;
    float* coord_new = h_new + (size_t)NN * 128;
    float* ef        = coord_new + (size_t)NN * 3;

    // ws layout (~42 MB). agg/tsum/deg contiguous for one memset.
    float*          agg    = (float*)d_ws;                              // [NN*128]
    float*          tsum   = agg + (size_t)NN * 128;                    // [NN*3]
    int*            deg    = (int*)(tsum + (size_t)NN * 3);             // [NN]
    int*            rowptr = deg + NN;                                  // [NN+1]
    int*            cursor = rowptr + NN + 1;                           // [NN]
    int*            elist  = cursor + NN;                               // [NE]
    unsigned short* hb     = (unsigned short*)(elist + NE);             // [NN*128]

    hipMemsetAsync(agg, 0, ((size_t)NN * 128 + (size_t)NN * 3 + NN) * sizeof(float), stream);

    k_prep   <<<1024, 512, 0, stream>>>(h, hb);
    k_deg    <<<1024, 256, 0, stream>>>(ei, deg);
    k_scan   <<<1,   1024, 0, stream>>>(deg, rowptr, cursor);
    k_scatter<<<1024, 256, 0, stream>>>(ei, cursor, elist);
    k_edge   <<<512,  512, 0, stream>>>(hb, coord, ei, elist, w_e1, b_e1,
                                        w_e2, b_e2, w_c1, b_c1, w_c2,
                                        ef, agg, tsum);
    k_node   <<<512,  512, 0, stream>>>(hb, h, agg, w_n1, b_n1, w_n2, b_n2,
                                        coord, tsum, rowptr, h_new, coord_new);
}

// Round 8
// 632.609 us; speedup vs baseline: 1.3165x; 1.1372x over previous
//
#include <hip/hip_runtime.h>

#define NN 50000
#define NE 600000

typedef __attribute__((ext_vector_type(8))) short short8;
typedef __attribute__((ext_vector_type(4))) float f32x4;

#define SWZ(row) ((((row) & 7) << 4) ^ (((row) & 8) << 2))

__device__ __forceinline__ float silu_f(float x) { return x / (1.0f + __expf(-x)); }

__device__ __forceinline__ unsigned short f2bf(float f) {
    unsigned u = __builtin_bit_cast(unsigned, f);
    unsigned r = u + 0x7FFFu + ((u >> 16) & 1u);   // RNE
    return (unsigned short)(r >> 16);
}

// LDS-only barrier (no vmcnt drain) — atomics/stores stay in flight.
__device__ __forceinline__ void lds_barrier() {
    asm volatile("s_waitcnt lgkmcnt(0)" ::: "memory");
    __builtin_amdgcn_s_barrier();
    asm volatile("" ::: "memory");
}

// 4x4 transpose across the 4 lanes of a quad (p = lane&3).
// In:  v[j] = M[row j][col p].  Out: v[j] = M[row p][col j].
// xor-1/xor-2 shuffles lower to quad_perm DPP (VALU, not DS).
__device__ __forceinline__ void xpose4(float v[4]) {
    const int p = threadIdx.x & 3;
    float s0 = (p & 1) ? v[0] : v[1];
    float s1 = (p & 1) ? v[2] : v[3];
    s0 = __shfl_xor(s0, 1);
    s1 = __shfl_xor(s1, 1);
    float w0 = (p & 1) ? s0 : v[0];
    float w1 = (p & 1) ? v[1] : s0;
    float w2 = (p & 1) ? s1 : v[2];
    float w3 = (p & 1) ? v[3] : s1;
    float t0 = (p & 2) ? w0 : w2;
    float t1 = (p & 2) ? w1 : w3;
    t0 = __shfl_xor(t0, 2);
    t1 = __shfl_xor(t1, 2);
    v[0] = (p & 2) ? t0 : w0;
    v[2] = (p & 2) ? w2 : t0;
    v[1] = (p & 2) ? t1 : w1;
    v[3] = (p & 2) ? w3 : t1;
}

__device__ __forceinline__ unsigned cvt_pk_bf16(float lo, float hi) {
    unsigned r;
    asm("v_cvt_pk_bf16_f32 %0, %1, %2" : "=v"(r) : "v"(lo), "v"(hi));
    return r;
}

// ---------------------------------------------------------------------------
// K0: h (fp32) -> h_bf16
// ---------------------------------------------------------------------------
__global__ __launch_bounds__(512) void k_prep(const float* __restrict__ h,
                                              unsigned short* __restrict__ hb)
{
    const int nchunks = NN * 128 / 8;   // 800000
    for (int i = blockIdx.x * blockDim.x + threadIdx.x; i < nchunks;
         i += gridDim.x * blockDim.x) {
        const float4* p = (const float4*)(h + (size_t)i * 8);
        float4 x = p[0], y = p[1];
        short8 v;
        v[0] = f2bf(x.x); v[1] = f2bf(x.y); v[2] = f2bf(x.z); v[3] = f2bf(x.w);
        v[4] = f2bf(y.x); v[5] = f2bf(y.y); v[6] = f2bf(y.z); v[7] = f2bf(y.w);
        *(short8*)(hb + (size_t)i * 8) = v;
    }
}

// ---------------------------------------------------------------------------
// CSR build: deg count -> 1-block scan -> scatter
// ---------------------------------------------------------------------------
__global__ __launch_bounds__(256) void k_deg(const int* __restrict__ ei,
                                             int* __restrict__ deg)
{
    for (int e = blockIdx.x * 256 + threadIdx.x; e < NE; e += gridDim.x * 256)
        atomicAdd(&deg[ei[e]], 1);
}

__global__ __launch_bounds__(1024) void k_scan(const int* __restrict__ deg,
                                               int* __restrict__ rowptr,
                                               int* __restrict__ cursor)
{
    __shared__ int sb[1024];
    const int t = threadIdx.x;
    const int CH = 49;
    const int base = t * CH;
    int s = 0;
    for (int j = 0; j < CH; ++j) {
        int idx = base + j;
        if (idx < NN) s += deg[idx];
    }
    sb[t] = s;
    __syncthreads();
    for (int off = 1; off < 1024; off <<= 1) {
        int v = (t >= off) ? sb[t - off] : 0;
        __syncthreads();
        sb[t] += v;
        __syncthreads();
    }
    int run = sb[t] - s;
    for (int j = 0; j < CH; ++j) {
        int idx = base + j;
        if (idx < NN) {
            rowptr[idx] = run;
            cursor[idx] = run;
            run += deg[idx];
        }
    }
    if (t == 1023) rowptr[NN] = sb[1023];
}

__global__ __launch_bounds__(256) void k_scatter(const int* __restrict__ ei,
                                                 int* __restrict__ cursor,
                                                 int* __restrict__ elist)
{
    for (int e = blockIdx.x * 256 + threadIdx.x; e < NE; e += gridDim.x * 256) {
        int pos = atomicAdd(&cursor[ei[e]], 1);
        elist[pos] = e;
    }
}

// ---------------------------------------------------------------------------
// K1: edge MLP only (CSR order). Per 64-edge tile, 4 lgkm barriers:
//  stage | G1 + packed-epi1 | G2 + packed-epi2 (ef f32x4 nt + EF->A1s b64) |
//  seg-reduce (b64 reads, one atomic per distinct row x col) |
// ---------------------------------------------------------------------------
__global__ __launch_bounds__(512, 8) void k_edge(
    const unsigned short* __restrict__ hb, const float* __restrict__ coord,
    const int* __restrict__ ei, const int* __restrict__ elist,
    const float* __restrict__ w_e1, const float* __restrict__ b_e1,
    const float* __restrict__ w_e2, const float* __restrict__ b_e2,
    float* __restrict__ ef, float* __restrict__ agg)
{
    __shared__ unsigned short A1s[64 * 256];    // 32 KB (h-pair; later EF bf16)
    __shared__ unsigned short A2s[64 * 128];    // 16 KB (t1 bf16)
    __shared__ float rad[64];
    __shared__ int   es_s[64];
    __shared__ int   seg_start[65];
    __shared__ int   seg_row[64];
    __shared__ int   nseg_s;

    const int tid  = threadIdx.x;
    const int wv   = tid >> 6, lane = tid & 63;
    const int l4   = lane >> 4, li = lane & 15;
    const int n    = wv * 16 + li;              // this wave's output column

    short8 bw1[8], bw2[4];
    #pragma unroll
    for (int ks = 0; ks < 8; ++ks) {
        short8 t;
        #pragma unroll
        for (int j = 0; j < 8; ++j) t[j] = f2bf(w_e1[(ks * 32 + l4 * 8 + j) * 128 + n]);
        bw1[ks] = t;
    }
    #pragma unroll
    for (int ks = 0; ks < 4; ++ks) {
        short8 t;
        #pragma unroll
        for (int j = 0; j < 8; ++j) t[j] = f2bf(w_e2[(ks * 32 + l4 * 8 + j) * 128 + n]);
        bw2[ks] = t;
    }
    const float wradv = w_e1[256 * 128 + n];
    const float b1v = b_e1[n], b2v = b_e2[n];

    const f32x4 z4 = {0.f, 0.f, 0.f, 0.f};
    const int colb = wv * 16 + (li >> 2) * 4;   // transposed col base
    const int pp   = li & 3;

    for (int t = blockIdx.x; t < NE / 64; t += gridDim.x) {
        const int ebase = t * 64;
        // ---- wave 0: edge ids, radial, segment table ----
        if (tid < 64) {
            int e = elist[ebase + tid];
            int r = ei[e], c = ei[NE + e];
            es_s[tid] = e;
            float dx = coord[r * 3 + 0] - coord[c * 3 + 0];
            float dy = coord[r * 3 + 1] - coord[c * 3 + 1];
            float dz = coord[r * 3 + 2] - coord[c * 3 + 2];
            rad[tid] = dx * dx + dy * dy + dz * dz;
            int prev = __shfl_up(r, 1);
            bool flag = (lane == 0) || (r != prev);
            unsigned long long mask = __ballot(flag);
            if (flag) {
                int pos = __popcll(mask & ((1ull << lane) - 1ull));
                seg_start[pos] = lane;
                seg_row[pos]   = r;
            }
            if (lane == 0) {
                int ns = __popcll(mask);
                nseg_s = ns;
                seg_start[ns] = 64;
            }
        }
        // ---- stage A1: 64 edges x 32 chunks (16B) ----
        {
            int le = tid >> 3;
            int e = elist[ebase + le];
            int r = ei[e], c = ei[NE + e];
            const unsigned short* hr = hb + (size_t)r * 128;
            const unsigned short* hc = hb + (size_t)c * 128;
            #pragma unroll
            for (int i = 0; i < 4; ++i) {
                int chunk = i * 8 + (tid & 7);
                short8 v = (chunk < 16) ? *(const short8*)(hr + chunk * 8)
                                        : *(const short8*)(hc + (chunk - 16) * 8);
                int off = le * 512 + ((chunk * 16) ^ SWZ(le));
                *(short8*)((char*)A1s + off) = v;
            }
        }
        lds_barrier();   // B1

        // ---- GEMM1: [64 x 256] @ [256 x 16] ----
        f32x4 acc[4];
        acc[0] = z4; acc[1] = z4; acc[2] = z4; acc[3] = z4;
        for (int ks = 0; ks < 8; ++ks) {
            const int kb = ks * 64 + l4 * 16;
            #pragma unroll
            for (int mf = 0; mf < 4; ++mf) {
                int row = mf * 16 + li;
                short8 a = *(const short8*)((const char*)A1s + row * 512 + (kb ^ SWZ(row)));
                acc[mf] = __builtin_amdgcn_mfma_f32_16x16x32_bf16(a, bw1[ks], acc[mf], 0, 0, 0);
            }
        }
        // epi1: bias + radial rank-1 + silu -> transpose -> packed b64 to A2s
        #pragma unroll
        for (int mf = 0; mf < 4; ++mf) {
            float4 rr = *(const float4*)&rad[mf * 16 + l4 * 4];
            float v[4];
            v[0] = silu_f(acc[mf][0] + rr.x * wradv + b1v);
            v[1] = silu_f(acc[mf][1] + rr.y * wradv + b1v);
            v[2] = silu_f(acc[mf][2] + rr.z * wradv + b1v);
            v[3] = silu_f(acc[mf][3] + rr.w * wradv + b1v);
            xpose4(v);
            int row = mf * 16 + l4 * 4 + pp;
            uint2 d;
            d.x = cvt_pk_bf16(v[0], v[1]);
            d.y = cvt_pk_bf16(v[2], v[3]);
            *(uint2*)((char*)A2s + row * 256 + ((colb * 2) ^ SWZ(row))) = d;
        }
        lds_barrier();   // B2: A2s ready; A1s reads done

        // ---- GEMM2: [64 x 128] @ [128 x 16] ----
        acc[0] = z4; acc[1] = z4; acc[2] = z4; acc[3] = z4;
        for (int ks = 0; ks < 4; ++ks) {
            const int kb = ks * 64 + l4 * 16;
            #pragma unroll
            for (int mf = 0; mf < 4; ++mf) {
                int row = mf * 16 + li;
                short8 a = *(const short8*)((const char*)A2s + row * 256 + (kb ^ SWZ(row)));
                acc[mf] = __builtin_amdgcn_mfma_f32_16x16x32_bf16(a, bw2[ks], acc[mf], 0, 0, 0);
            }
        }
        // epi2: bias+silu -> transpose -> EF b64 to A1s + ef f32x4 nt-store
        #pragma unroll
        for (int mf = 0; mf < 4; ++mf) {
            float v[4];
            v[0] = silu_f(acc[mf][0] + b2v);
            v[1] = silu_f(acc[mf][1] + b2v);
            v[2] = silu_f(acc[mf][2] + b2v);
            v[3] = silu_f(acc[mf][3] + b2v);
            xpose4(v);
            int row = mf * 16 + l4 * 4 + pp;
            uint2 d;
            d.x = cvt_pk_bf16(v[0], v[1]);
            d.y = cvt_pk_bf16(v[2], v[3]);
            *(uint2*)((char*)A1s + row * 256 + ((colb * 2) ^ SWZ(row))) = d;
            int e = es_s[row];
            f32x4 o = {v[0], v[1], v[2], v[3]};
            __builtin_nontemporal_store(o, (f32x4*)&ef[(size_t)e * 128 + colb]);
        }
        lds_barrier();   // B3: EF(A1s) complete

        // ---- seg-reduce: thread = (col-group of 4, seg slot) ----
        {
            const int cg = tid & 31;          // cols 4cg..4cg+3
            const int ns = nseg_s;
            for (int s = tid >> 5; s < ns; s += 16) {
                int i0 = seg_start[s], i1 = seg_start[s + 1];
                float s0 = 0.f, s1 = 0.f, s2 = 0.f, s3 = 0.f;
                for (int i = i0; i < i1; ++i) {
                    uint2 d = *(const uint2*)((const char*)A1s + i * 256 + ((cg * 8) ^ SWZ(i)));
                    s0 += __builtin_bit_cast(float, d.x << 16);
                    s1 += __builtin_bit_cast(float, d.x & 0xffff0000u);
                    s2 += __builtin_bit_cast(float, d.y << 16);
                    s3 += __builtin_bit_cast(float, d.y & 0xffff0000u);
                }
                float* ap = &agg[(size_t)seg_row[s] * 128 + cg * 4];
                atomicAdd(ap + 0, s0);
                atomicAdd(ap + 1, s1);
                atomicAdd(ap + 2, s2);
                atomicAdd(ap + 3, s3);
            }
        }
        lds_barrier();   // B4: A1s/seg reads done before next stage
    }
}

// ---------------------------------------------------------------------------
// K-coord: streaming coord MLP (original edge order).
//   wq = silu(ef @ w_c1 + b_c1) @ w_c2 ; tsum[row] += coord_diff * wq
// Swapped-operand GEMM: Wc1^T(A) x EF^T(B) -> edge lives in lane.
// 8 waves: edge-half (w&1)*64, feat-quarter (w>>1)*32. 2 lgkm barriers.
// ---------------------------------------------------------------------------
__global__ __launch_bounds__(512, 4) void k_coord(
    const float* __restrict__ ef, const float* __restrict__ coord,
    const int* __restrict__ ei,
    const float* __restrict__ w_c1, const float* __restrict__ b_c1,
    const float* __restrict__ w_c2,
    float* __restrict__ tsum)
{
    __shared__ unsigned short EFs[128 * 128];   // 32 KB, [edge][k] swizzled
    __shared__ float wqp[4][128];

    const int tid  = threadIdx.x;
    const int wv   = tid >> 6, lane = tid & 63;
    const int l4   = lane >> 4, li = lane & 15;
    const int eh   = (wv & 1) * 64;             // edge-half base
    const int fq   = (wv >> 1) * 32;            // feat-quarter base

    short8 wa[2][4];
    #pragma unroll
    for (int mf = 0; mf < 2; ++mf)
        #pragma unroll
        for (int ks = 0; ks < 4; ++ks) {
            short8 t;
            #pragma unroll
            for (int j = 0; j < 8; ++j)
                t[j] = f2bf(w_c1[(ks * 32 + l4 * 8 + j) * 128 + fq + mf * 16 + li]);
            wa[mf][ks] = t;
        }
    float bcv[2][4], wcv[2][4];
    #pragma unroll
    for (int mf = 0; mf < 2; ++mf)
        #pragma unroll
        for (int r = 0; r < 4; ++r) {
            int feat = fq + mf * 16 + l4 * 4 + r;
            bcv[mf][r] = b_c1[feat];
            wcv[mf][r] = w_c2[feat];
        }

    const f32x4 z4 = {0.f, 0.f, 0.f, 0.f};
    const int ntiles = (NE + 127) / 128;

    for (int t = blockIdx.x; t < ntiles; t += gridDim.x) {
        const int ebase = t * 128;
        // stage ef -> bf16 LDS: thread = (edge row tid>>2, 32-col chunk tid&3)
        {
            int row = tid >> 2;
            int e = ebase + row;
            int cb = (tid & 3) * 32;
            #pragma unroll
            for (int i = 0; i < 2; ++i) {
                int c0 = cb + i * 16;
                short8 v;
                if (e < NE) {
                    const float4* p = (const float4*)(ef + (size_t)e * 128 + c0);
                    float4 x = p[0], y = p[1];
                    v[0] = f2bf(x.x); v[1] = f2bf(x.y); v[2] = f2bf(x.z); v[3] = f2bf(x.w);
                    v[4] = f2bf(y.x); v[5] = f2bf(y.y); v[6] = f2bf(y.z); v[7] = f2bf(y.w);
                } else v = (short8)0;
                *(short8*)((char*)EFs + row * 256 + ((c0 * 2) ^ SWZ(row))) = v;
                int c1 = c0 + 8;
                short8 w;
                if (e < NE) {
                    const float4* q = (const float4*)(ef + (size_t)e * 128 + c1);
                    float4 x = q[0], y = q[1];
                    w[0] = f2bf(x.x); w[1] = f2bf(x.y); w[2] = f2bf(x.z); w[3] = f2bf(x.w);
                    w[4] = f2bf(y.x); w[5] = f2bf(y.y); w[6] = f2bf(y.z); w[7] = f2bf(y.w);
                } else w = (short8)0;
                *(short8*)((char*)EFs + row * 256 + ((c1 * 2) ^ SWZ(row))) = w;
            }
        }
        lds_barrier();   // B1

        f32x4 acc[2][4];
        #pragma unroll
        for (int mf = 0; mf < 2; ++mf)
            #pragma unroll
            for (int nf = 0; nf < 4; ++nf) acc[mf][nf] = z4;
        for (int ks = 0; ks < 4; ++ks) {
            const int kb = ks * 64 + l4 * 16;
            #pragma unroll
            for (int nf = 0; nf < 4; ++nf) {
                int edge = eh + nf * 16 + li;
                short8 b = *(const short8*)((const char*)EFs + edge * 256 + (kb ^ SWZ(edge)));
                #pragma unroll
                for (int mf = 0; mf < 2; ++mf)
                    acc[mf][nf] = __builtin_amdgcn_mfma_f32_16x16x32_bf16(
                        wa[mf][ks], b, acc[mf][nf], 0, 0, 0);
            }
        }
        #pragma unroll
        for (int nf = 0; nf < 4; ++nf) {
            float p = 0.f;
            #pragma unroll
            for (int mf = 0; mf < 2; ++mf)
                #pragma unroll
                for (int r = 0; r < 4; ++r)
                    p += silu_f(acc[mf][nf][r] + bcv[mf][r]) * wcv[mf][r];
            p += __shfl_xor(p, 16);
            p += __shfl_xor(p, 32);
            if (l4 == 0) wqp[wv >> 1][eh + nf * 16 + li] = p;
        }
        lds_barrier();   // B2

        if (tid < 128) {
            float wq = wqp[0][tid] + wqp[1][tid] + wqp[2][tid] + wqp[3][tid];
            int e = ebase + tid;
            if (e < NE) {
                int r = ei[e], c = ei[NE + e];
                float dx = coord[r * 3 + 0] - coord[c * 3 + 0];
                float dy = coord[r * 3 + 1] - coord[c * 3 + 1];
                float dz = coord[r * 3 + 2] - coord[c * 3 + 2];
                atomicAdd(&tsum[r * 3 + 0], dx * wq);
                atomicAdd(&tsum[r * 3 + 1], dy * wq);
                atomicAdd(&tsum[r * 3 + 2], dz * wq);
            }
        }
        // wqp re-written only after B1(t+1); EFs re-staged after B2 — safe.
    }
}

// ---------------------------------------------------------------------------
// K2: fused node MLP + coord_new. Packed epilogues, 2 lgkm barriers.
// ---------------------------------------------------------------------------
__global__ __launch_bounds__(512, 8) void k_node(
    const unsigned short* __restrict__ hb, const float* __restrict__ h,
    const float* __restrict__ agg,
    const float* __restrict__ w_n1, const float* __restrict__ b_n1,
    const float* __restrict__ w_n2, const float* __restrict__ b_n2,
    const float* __restrict__ coord, const float* __restrict__ tsum,
    const int* __restrict__ rowptr,
    float* __restrict__ h_new, float* __restrict__ coord_new)
{
    __shared__ unsigned short As[64 * 256];     // 32 KB
    __shared__ unsigned short Us[64 * 128];     // 16 KB

    const int tid  = threadIdx.x;
    const int wv   = tid >> 6, lane = tid & 63;
    const int l4   = lane >> 4, li = lane & 15;
    const int n    = wv * 16 + li;

    short8 bw1[8], bw2[4];
    #pragma unroll
    for (int ks = 0; ks < 8; ++ks) {
        short8 t;
        #pragma unroll
        for (int j = 0; j < 8; ++j) t[j] = f2bf(w_n1[(ks * 32 + l4 * 8 + j) * 128 + n]);
        bw1[ks] = t;
    }
    #pragma unroll
    for (int ks = 0; ks < 4; ++ks) {
        short8 t;
        #pragma unroll
        for (int j = 0; j < 8; ++j) t[j] = f2bf(w_n2[(ks * 32 + l4 * 8 + j) * 128 + n]);
        bw2[ks] = t;
    }
    const float b1v = b_n1[n], b2v = b_n2[n];

    const f32x4 z4 = {0.f, 0.f, 0.f, 0.f};
    const int ntiles = (NN + 63) / 64;
    const int colb = wv * 16 + (li >> 2) * 4;
    const int pp   = li & 3;

    for (int t = blockIdx.x; t < ntiles; t += gridDim.x) {
        const int nbase = t * 64;
        {
            int ln = tid >> 3;
            int node = nbase + ln;
            #pragma unroll
            for (int i = 0; i < 4; ++i) {
                int chunk = i * 8 + (tid & 7);
                short8 v;
                if (node < NN) {
                    if (chunk < 16) {
                        v = *(const short8*)(hb + (size_t)node * 128 + chunk * 8);
                    } else {
                        const float4* p = (const float4*)(agg + (size_t)node * 128 + (chunk - 16) * 8);
                        float4 x = p[0], y = p[1];
                        v[0] = f2bf(x.x); v[1] = f2bf(x.y); v[2] = f2bf(x.z); v[3] = f2bf(x.w);
                        v[4] = f2bf(y.x); v[5] = f2bf(y.y); v[6] = f2bf(y.z); v[7] = f2bf(y.w);
                    }
                } else v = (short8)0;
                int off = ln * 512 + ((chunk * 16) ^ SWZ(ln));
                *(short8*)((char*)As + off) = v;
            }
        }
        lds_barrier();   // B1

        f32x4 acc[4];
        acc[0] = z4; acc[1] = z4; acc[2] = z4; acc[3] = z4;
        for (int ks = 0; ks < 8; ++ks) {
            const int kb = ks * 64 + l4 * 16;
            #pragma unroll
            for (int mf = 0; mf < 4; ++mf) {
                int row = mf * 16 + li;
                short8 a = *(const short8*)((const char*)As + row * 512 + (kb ^ SWZ(row)));
                acc[mf] = __builtin_amdgcn_mfma_f32_16x16x32_bf16(a, bw1[ks], acc[mf], 0, 0, 0);
            }
        }
        #pragma unroll
        for (int mf = 0; mf < 4; ++mf) {
            float v[4];
            v[0] = silu_f(acc[mf][0] + b1v);
            v[1] = silu_f(acc[mf][1] + b1v);
            v[2] = silu_f(acc[mf][2] + b1v);
            v[3] = silu_f(acc[mf][3] + b1v);
            xpose4(v);
            int row = mf * 16 + l4 * 4 + pp;
            uint2 d;
            d.x = cvt_pk_bf16(v[0], v[1]);
            d.y = cvt_pk_bf16(v[2], v[3]);
            *(uint2*)((char*)Us + row * 256 + ((colb * 2) ^ SWZ(row))) = d;
        }
        lds_barrier();   // B2

        acc[0] = z4; acc[1] = z4; acc[2] = z4; acc[3] = z4;
        for (int ks = 0; ks < 4; ++ks) {
            const int kb = ks * 64 + l4 * 16;
            #pragma unroll
            for (int mf = 0; mf < 4; ++mf) {
                int row = mf * 16 + li;
                short8 a = *(const short8*)((const char*)Us + row * 256 + (kb ^ SWZ(row)));
                acc[mf] = __builtin_amdgcn_mfma_f32_16x16x32_bf16(a, bw2[ks], acc[mf], 0, 0, 0);
            }
        }
        #pragma unroll
        for (int mf = 0; mf < 4; ++mf) {
            float v[4];
            v[0] = acc[mf][0] + b2v;
            v[1] = acc[mf][1] + b2v;
            v[2] = acc[mf][2] + b2v;
            v[3] = acc[mf][3] + b2v;
            xpose4(v);
            int row = mf * 16 + l4 * 4 + pp;
            int node = nbase + row;
            if (node < NN) {
                const f32x4 h4 = *(const f32x4*)&h[(size_t)node * 128 + colb];
                f32x4 o = {v[0] + h4.x, v[1] + h4.y, v[2] + h4.z, v[3] + h4.w};
                __builtin_nontemporal_store(o, (f32x4*)&h_new[(size_t)node * 128 + colb]);
            }
        }
        if (tid < 64) {
            int node = nbase + tid;
            if (node < NN) {
                int deg = rowptr[node + 1] - rowptr[node];
                float m = fmaxf((float)deg, 1.0f);
                coord_new[node * 3 + 0] = coord[node * 3 + 0] + tsum[node * 3 + 0] / m;
                coord_new[node * 3 + 1] = coord[node * 3 + 1] + tsum[node * 3 + 1] / m;
                coord_new[node * 3 + 2] = coord[node * 3 + 2] + tsum[node * 3 + 2] / m;
            }
        }
    }
}

extern "C" void kernel_launch(void* const* d_in, const int* in_sizes, int n_in,
                              void* d_out, int out_size, void* d_ws, size_t ws_size,
                              hipStream_t stream)
{
    const float* h     = (const float*)d_in[0];
    const float* coord = (const float*)d_in[1];
    const int*   ei    = (const int*)d_in[2];
    const float* w_e1  = (const float*)d_in[3];
    const float* b_e1  = (const float*)d_in[4];
    const float* w_e2  = (const float*)d_in[5];
    const float* b_e2  = (const float*)d_in[6];
    const float* w_n1  = (const float*)d_in[7];
    const float* b_n1  = (const float*)d_in[8];
    const float* w_n2  = (const float*)d_in[9];
    const float* b_n2  = (const float*)d_in[10];
    const float* w_c1  = (const float*)d_in[11];
    const float* b_c1  = (const float*)d_in[12];
    const float* w_c2  = (const float*)d_in[13];

    float* h_new     = (float*)d_out;
    float* coord_new = h_new + (size_t)NN * 128;
    float* ef        = coord_new + (size_t)NN * 3;

    float*          agg    = (float*)d_ws;                              // [NN*128]
    float*          tsum   = agg + (size_t)NN * 128;                    // [NN*3]
    int*            deg    = (int*)(tsum + (size_t)NN * 3);             // [NN]
    int*            rowptr = deg + NN;                                  // [NN+1]
    int*            cursor = rowptr + NN + 1;                           // [NN]
    int*            elist  = cursor + NN;                               // [NE]
    unsigned short* hb     = (unsigned short*)(elist + NE);             // [NN*128]

    hipMemsetAsync(agg, 0, ((size_t)NN * 128 + (size_t)NN * 3 + NN) * sizeof(float), stream);

    k_prep   <<<1024, 512, 0, stream>>>(h, hb);
    k_deg    <<<1024, 256, 0, stream>>>(ei, deg);
    k_scan   <<<1,   1024, 0, stream>>>(deg, rowptr, cursor);
    k_scatter<<<1024, 256, 0, stream>>>(ei, cursor, elist);
    k_edge   <<<768,  512, 0, stream>>>(hb, coord, ei, elist, w_e1, b_e1,
                                        w_e2, b_e2, ef, agg);
    k_coord  <<<512,  512, 0, stream>>>(ef, coord, ei, w_c1, b_c1, w_c2, tsum);
    k_node   <<<768,  512, 0, stream>>>(hb, h, agg, w_n1, b_n1, w_n2, b_n2,
                                        coord, tsum, rowptr, h_new, coord_new);
}